// Round 1
// baseline (35.837 us; speedup 1.0000x reference)
//
#include <hip/hip_runtime.h>

// LIF current encoder (norse lif_current_encoder), unrolled 32 steps.
//   v' = v + DT*TAU_MEM_INV*((V_LEAK - v) + x) = v + 0.1f*(x - v)
//   z  = (v' - V_TH >= 0) ? 1 : 0
//   v' = v' - z*(v' - V_RESET)   (i.e. reset to 0 on spike)
// Output layout: zs[t][b][c][h][w] -> out[t*N + i], float32.
// Pure streaming: 6.3 MB read, 201.3 MB write -> write-BW-bound.

#define SEQ_LEN 32

__global__ __launch_bounds__(256) void lif_encode_kernel(
    const float4* __restrict__ X, float4* __restrict__ out, int n4)
{
    int i = blockIdx.x * blockDim.x + threadIdx.x;
    if (i >= n4) return;

    float4 x = X[i];
    float vx = 0.0f, vy = 0.0f, vz = 0.0f, vw = 0.0f;

#pragma unroll
    for (int t = 0; t < SEQ_LEN; ++t) {
        // membrane update (same expression shape as reference; exact in IEEE:
        // (0 - v) + x == x - v)
        vx = vx + 0.1f * (x.x - vx);
        vy = vy + 0.1f * (x.y - vy);
        vz = vz + 0.1f * (x.z - vz);
        vw = vw + 0.1f * (x.w - vw);

        float4 z;
        z.x = (vx >= 1.0f) ? 1.0f : 0.0f;
        z.y = (vy >= 1.0f) ? 1.0f : 0.0f;
        z.z = (vz >= 1.0f) ? 1.0f : 0.0f;
        z.w = (vw >= 1.0f) ? 1.0f : 0.0f;

        // reset: v - z*(v - 0) -> 0 exactly when z==1
        vx = (vx >= 1.0f) ? 0.0f : vx;
        vy = (vy >= 1.0f) ? 0.0f : vy;
        vz = (vz >= 1.0f) ? 0.0f : vz;
        vw = (vw >= 1.0f) ? 0.0f : vw;

        out[(size_t)t * (size_t)n4 + (size_t)i] = z;
    }
}

extern "C" void kernel_launch(void* const* d_in, const int* in_sizes, int n_in,
                              void* d_out, int out_size, void* d_ws, size_t ws_size,
                              hipStream_t stream) {
    const float4* X = (const float4*)d_in[0];
    float4* out = (float4*)d_out;

    int n = in_sizes[0];      // 1,572,864 (divisible by 4)
    int n4 = n / 4;           // 393,216 float4 elements per timestep

    const int block = 256;
    const int grid = (n4 + block - 1) / block;   // 1536 blocks
    lif_encode_kernel<<<grid, block, 0, stream>>>(X, out, n4);
}